// Round 3
// baseline (126.511 us; speedup 1.0000x reference)
//
#include <hip/hip_runtime.h>

constexpr int BATCH = 131072;
constexpr int T = 10;
constexpr int H = 32;

// ws layout (floats): [0 .. 33*32)  = 33 rows x 32:
//   rows 0..31: W_hh^T  (row k = column k of W_hh)
//   row  32   : W_ih    (x is treated as the 33rd hidden element)
// [33*32 .. 33*32+32) = b_ih + b_hh
__global__ void __launch_bounds__(1024)
rnn_setup(const float* __restrict__ W_ih, const float* __restrict__ W_hh,
          const float* __restrict__ b_ih, const float* __restrict__ b_hh,
          float* __restrict__ ws) {
    const int i = threadIdx.x;            // 0..1023
    const int j = i >> 5, k = i & 31;
    ws[k * H + j] = W_hh[i];              // transpose
    if (i < H) {
        ws[H * H + i]     = W_ih[i];      // row 32
        ws[33 * H + i]    = b_ih[i] + b_hh[i];
    }
}

__global__ void __launch_bounds__(256, 2)
rnn_main(const float* __restrict__ x,      // [B, T]
         const float* __restrict__ h0,     // [B, H]
         const float* __restrict__ w,      // ws: 33x32 wT rows + bias
         const float* __restrict__ W_out,  // [H]
         const float* __restrict__ b_out,  // [1]
         float* __restrict__ out)          // outs [B*T] then hT [B*H]
{
    const int b = blockIdx.x * 256 + threadIdx.x;
    const float* __restrict__ bs = w + 33 * H;

    float h[H];
    {
        const float4* hp = reinterpret_cast<const float4*>(h0 + (size_t)b * H);
        #pragma unroll
        for (int i = 0; i < H / 4; ++i) {
            float4 v = hp[i];
            h[4*i+0] = v.x; h[4*i+1] = v.y; h[4*i+2] = v.z; h[4*i+3] = v.w;
        }
    }

    const float* xb = x + (size_t)b * T;
    float*       ob = out + (size_t)b * T;

    float xt = xb[0];

    #pragma unroll 1
    for (int t = 0; t < T; ++t) {
        float xnext = (t + 1 < T) ? xb[t + 1] : 0.0f;

        // k-outer / j-inner: 32 independent accumulator chains -> issue-bound.
        // Weight rows are wave-uniform scalar loads (s_load_dwordx16 pairs).
        float acc[H];
        #pragma unroll
        for (int j = 0; j < H; ++j) acc[j] = bs[j];

        #pragma unroll
        for (int k = 0; k <= H; ++k) {            // 33 rows; row 32 pairs with xt
            const float hk = (k < H) ? h[k] : xt;
            const float* __restrict__ wr = w + k * H;
            #pragma unroll
            for (int j = 0; j < H; ++j)
                acc[j] = fmaf(hk, wr[j], acc[j]); // 1 SGPR operand: legal v_fma
        }

        float o = b_out[0];
        #pragma unroll
        for (int j = 0; j < H; ++j) {
            // tanh(v) = 1 - 2/(exp(2v)+1); overflow-safe at both ends
            float e  = __expf(2.0f * acc[j]);
            float hn = 1.0f - 2.0f * __builtin_amdgcn_rcpf(e + 1.0f);
            h[j] = hn;
            o = fmaf(hn, W_out[j], o);
        }
        ob[t] = o;
        xt = xnext;
    }

    float4* hout = reinterpret_cast<float4*>(out + (size_t)BATCH * T + (size_t)b * H);
    #pragma unroll
    for (int i = 0; i < H / 4; ++i) {
        float4 v;
        v.x = h[4*i+0]; v.y = h[4*i+1]; v.z = h[4*i+2]; v.w = h[4*i+3];
        hout[i] = v;
    }
}

extern "C" void kernel_launch(void* const* d_in, const int* in_sizes, int n_in,
                              void* d_out, int out_size, void* d_ws, size_t ws_size,
                              hipStream_t stream) {
    const float* x     = (const float*)d_in[0];
    const float* h0    = (const float*)d_in[1];
    const float* W_ih  = (const float*)d_in[2];
    const float* W_hh  = (const float*)d_in[3];
    const float* b_ih  = (const float*)d_in[4];
    const float* b_hh  = (const float*)d_in[5];
    const float* W_out = (const float*)d_in[6];
    const float* b_out = (const float*)d_in[7];
    float* out = (float*)d_out;
    float* ws  = (float*)d_ws;

    rnn_setup<<<1, 1024, 0, stream>>>(W_ih, W_hh, b_ih, b_hh, ws);
    rnn_main<<<BATCH / 256, 256, 0, stream>>>(
        x, h0, ws, W_out, b_out, out);
}